// Round 4
// baseline (499.317 us; speedup 1.0000x reference)
//
#include <hip/hip_runtime.h>

#define NN 50000
#define MP 50048        // 391*128 padded rows
#define EE 800000
#define RCOLS 2304      // (R+1)*256; cols [2048,2304) = self-loop block

typedef __attribute__((ext_vector_type(8))) short short8;
typedef __attribute__((ext_vector_type(4))) float f32x4;

__device__ __forceinline__ float bf2f(unsigned short u) {
  unsigned int x = ((unsigned int)u) << 16;
  float f; __builtin_memcpy(&f, &x, 4); return f;
}
__device__ __forceinline__ unsigned short f2bf(float f) {
  unsigned int x; __builtin_memcpy(&x, &f, 4);
  return (unsigned short)((x + 0x7fffu + ((x >> 16) & 1u)) >> 16);
}

// ws layout (bytes)
constexpr size_t OFF_XB   = 0;                 // MP*256*2      = 25,624,576
constexpr size_t OFF_WT   = 25624576;          // 2304*256*2    =  1,179,648
constexpr size_t OFF_T    = 26804224;          // MP*2304*2     = 230,621,184
constexpr size_t OFF_CNT  = 257425408;         // NN*4
constexpr size_t OFF_OFFS = 257625408;         // (NN+1)*4
constexpr size_t OFF_CUR  = 257825412;         // NN*4
constexpr size_t OFF_EIX  = 258025412;         // EE*4  -> total ~261.2MB

// ---- build W^T bf16 [2304][256]: rows 0..2047 = basis-combined W_r^T, rows 2048+ = loop_weight^T
__global__ __launch_bounds__(256) void build_w_kernel(
    const float* __restrict__ bases, const float* __restrict__ comp,
    const float* __restrict__ loopw, unsigned short* __restrict__ WT) {
  int idx = blockIdx.x * 256 + threadIdx.x;
  if (idx >= RCOLS * 256) return;
  int ogl = idx >> 8;       // output column index (0..2303)
  int i   = idx & 255;      // K index
  float v;
  if (ogl < 2048) {
    int r = ogl >> 8, o = ogl & 255;
    v = 0.f;
#pragma unroll
    for (int b = 0; b < 4; ++b)
      v += comp[r * 4 + b] * bases[((size_t)b * 256 + i) * 256 + o];
  } else {
    v = loopw[i * 256 + (ogl & 255)];
  }
  WT[idx] = f2bf(v);
}

// ---- convert X fp32 -> bf16, zero-pad rows [NN, MP)
__global__ __launch_bounds__(256) void convert_x_kernel(
    const float* __restrict__ X, unsigned short* __restrict__ Xb) {
  size_t e0 = ((size_t)blockIdx.x * 256 + threadIdx.x) * 4;
  if (e0 >= (size_t)MP * 256) return;
  float4 v = make_float4(0.f, 0.f, 0.f, 0.f);
  if (e0 < (size_t)NN * 256) v = *(const float4*)(X + e0);
  ushort4 o;
  o.x = f2bf(v.x); o.y = f2bf(v.y); o.z = f2bf(v.z); o.w = f2bf(v.w);
  *(ushort4*)(Xb + e0) = o;
}

// ---- bf16 MFMA GEMM: C[MP][2304] = A[MP][256] * Bt[2304][256]^T  (m97-style 128x128x64)
__global__ __launch_bounds__(256) void gemm_kernel(
    const unsigned short* __restrict__ A,
    const unsigned short* __restrict__ Bt,
    unsigned short* __restrict__ C) {
  __shared__ __align__(16) unsigned short As[128 * 64];
  __shared__ __align__(16) unsigned short Bs[128 * 64];
  const int tid  = threadIdx.x;
  const int lane = tid & 63;
  const int wave = tid >> 6;
  const int wm = wave >> 1, wn = wave & 1;
  const int m0 = blockIdx.x * 128;
  const int n0 = blockIdx.y * 128;

  f32x4 acc[4][4] = {};

  const int srow = tid >> 3;
  const int ke   = (tid & 7) * 8;
  const unsigned int ldsbase = (unsigned int)((tid & ~63) * 16);

  for (int k0 = 0; k0 < 256; k0 += 64) {
#pragma unroll
    for (int p = 0; p < 4; ++p) {
      int row = p * 32 + srow;
      const unsigned short* ga = A  + (size_t)(m0 + row) * 256 + k0 + ke;
      const unsigned short* gb = Bt + (size_t)(n0 + row) * 256 + k0 + ke;
      unsigned int lo = p * 4096 + ldsbase;
      __builtin_amdgcn_global_load_lds(
          (const __attribute__((address_space(1))) unsigned int*)ga,
          (__attribute__((address_space(3))) unsigned int*)((char*)As + lo), 16, 0, 0);
      __builtin_amdgcn_global_load_lds(
          (const __attribute__((address_space(1))) unsigned int*)gb,
          (__attribute__((address_space(3))) unsigned int*)((char*)Bs + lo), 16, 0, 0);
    }
    __syncthreads();

    const int rfr = lane & 15;
    const int kgr = (lane >> 4) * 8;
#pragma unroll
    for (int kk = 0; kk < 2; ++kk) {
      short8 af[4], bfr[4];
#pragma unroll
      for (int m = 0; m < 4; ++m)
        af[m] = *(const short8*)&As[(wm * 64 + m * 16 + rfr) * 64 + kk * 32 + kgr];
#pragma unroll
      for (int n = 0; n < 4; ++n)
        bfr[n] = *(const short8*)&Bs[(wn * 64 + n * 16 + rfr) * 64 + kk * 32 + kgr];
#pragma unroll
      for (int m = 0; m < 4; ++m)
#pragma unroll
        for (int n = 0; n < 4; ++n)
          acc[m][n] = __builtin_amdgcn_mfma_f32_16x16x32_bf16(af[m], bfr[n], acc[m][n], 0, 0, 0);
    }
    __syncthreads();
  }

  const int orow = (lane >> 4) * 4;
  const int ocol = lane & 15;
#pragma unroll
  for (int m = 0; m < 4; ++m)
#pragma unroll
    for (int n = 0; n < 4; ++n) {
      int gr = m0 + wm * 64 + m * 16 + orow;
      int gc = n0 + wn * 64 + n * 16 + ocol;
      unsigned short* cp = C + (size_t)gr * RCOLS + gc;
#pragma unroll
      for (int j = 0; j < 4; ++j)
        cp[(size_t)j * RCOLS] = f2bf(acc[m][n][j]);
    }
}

// ---- CSR build
__global__ __launch_bounds__(256) void count_kernel(const int* __restrict__ dst,
                                                    int* __restrict__ counts) {
  int e = blockIdx.x * 256 + threadIdx.x;
  if (e < EE) atomicAdd(&counts[dst[e]], 1);
}

__global__ __launch_bounds__(1024) void scan_kernel(const int* __restrict__ counts,
                                                    int* __restrict__ offsets) {
  __shared__ int wsum[16];
  __shared__ int carry_s;
  int tid = threadIdx.x, lane = tid & 63, wid = tid >> 6;
  if (tid == 0) carry_s = 0;
  __syncthreads();
  for (int base = 0; base < NN; base += 1024) {
    int i = base + tid;
    int v = (i < NN) ? counts[i] : 0;
    int incl = v;
#pragma unroll
    for (int d = 1; d < 64; d <<= 1) {
      int t = __shfl_up(incl, d, 64);
      if (lane >= d) incl += t;
    }
    if (lane == 63) wsum[wid] = incl;
    __syncthreads();
    int wpre = 0;
    for (int w = 0; w < wid; ++w) wpre += wsum[w];
    if (i < NN) offsets[i] = carry_s + wpre + incl - v;
    __syncthreads();
    if (tid == 1023) carry_s += wpre + incl;
    __syncthreads();
  }
  if (threadIdx.x == 0) offsets[NN] = carry_s;
}

__global__ __launch_bounds__(256) void scatter_kernel(
    const int* __restrict__ src, const int* __restrict__ dst,
    const int* __restrict__ etype, const int* __restrict__ offsets,
    int* __restrict__ cursor, unsigned int* __restrict__ eoff) {
  int e = blockIdx.x * 256 + threadIdx.x;
  if (e < EE) {
    int d = dst[e];
    int pos = atomicAdd(&cursor[d], 1);
    eoff[offsets[d] + pos] = (unsigned int)(src[e] * RCOLS + etype[e] * 256);
  }
}

// ---- gather-aggregate + self-loop + bias + LeakyReLU + LayerNorm; one wave per node
__global__ __launch_bounds__(256) void finalize_kernel(
    const unsigned short* __restrict__ T, const int* __restrict__ offsets,
    const unsigned int* __restrict__ eoff,
    const float* __restrict__ bias, const float* __restrict__ gamma,
    const float* __restrict__ beta, float* __restrict__ out) {
  int wid = threadIdx.x >> 6, lane = threadIdx.x & 63;
  int n = blockIdx.x * 4 + wid;           // grid 12500 * 4 waves = 50000 exactly
  int o4 = lane * 4;
  float a0 = 0.f, a1 = 0.f, a2 = 0.f, a3 = 0.f;
  int s = offsets[n], e = offsets[n + 1];
  for (int i = s; i < e; ++i) {
    ushort4 v = *(const ushort4*)(T + (size_t)eoff[i] + o4);
    a0 += bf2f(v.x); a1 += bf2f(v.y); a2 += bf2f(v.z); a3 += bf2f(v.w);
  }
  ushort4 sl = *(const ushort4*)(T + (size_t)n * RCOLS + 2048 + o4);
  float4 bi = *(const float4*)(bias + o4);
  a0 += bf2f(sl.x) + bi.x; a1 += bf2f(sl.y) + bi.y;
  a2 += bf2f(sl.z) + bi.z; a3 += bf2f(sl.w) + bi.w;
  a0 = a0 > 0.f ? a0 : 0.1f * a0;
  a1 = a1 > 0.f ? a1 : 0.1f * a1;
  a2 = a2 > 0.f ? a2 : 0.1f * a2;
  a3 = a3 > 0.f ? a3 : 0.1f * a3;
  float sum = a0 + a1 + a2 + a3;
  float sq  = a0 * a0 + a1 * a1 + a2 * a2 + a3 * a3;
#pragma unroll
  for (int m = 32; m >= 1; m >>= 1) {
    sum += __shfl_xor(sum, m);
    sq  += __shfl_xor(sq, m);
  }
  float mu  = sum * (1.f / 256.f);
  float var = sq * (1.f / 256.f) - mu * mu;
  float inv = rsqrtf(var + 1e-5f);
  float4 g = *(const float4*)(gamma + o4);
  float4 be = *(const float4*)(beta + o4);
  float4 o;
  o.x = g.x * (a0 - mu) * inv + be.x;
  o.y = g.y * (a1 - mu) * inv + be.y;
  o.z = g.z * (a2 - mu) * inv + be.z;
  o.w = g.w * (a3 - mu) * inv + be.w;
  *(float4*)(out + (size_t)n * 256 + o4) = o;
}

extern "C" void kernel_launch(void* const* d_in, const int* in_sizes, int n_in,
                              void* d_out, int out_size, void* d_ws, size_t ws_size,
                              hipStream_t stream) {
  const float* node_feats = (const float*)d_in[0];
  const int*   src        = (const int*)d_in[1];
  const int*   dst        = (const int*)d_in[2];
  const int*   etype      = (const int*)d_in[3];
  const float* bases      = (const float*)d_in[4];
  const float* comp       = (const float*)d_in[5];
  const float* loopw      = (const float*)d_in[6];
  const float* bias       = (const float*)d_in[7];
  const float* gamma      = (const float*)d_in[8];
  const float* beta       = (const float*)d_in[9];
  float* out = (float*)d_out;

  char* ws = (char*)d_ws;
  unsigned short* Xb   = (unsigned short*)(ws + OFF_XB);
  unsigned short* WT   = (unsigned short*)(ws + OFF_WT);
  unsigned short* T    = (unsigned short*)(ws + OFF_T);
  int*            cnts = (int*)(ws + OFF_CNT);
  int*            offs = (int*)(ws + OFF_OFFS);
  int*            cur  = (int*)(ws + OFF_CUR);
  unsigned int*   eoff = (unsigned int*)(ws + OFF_EIX);

  build_w_kernel<<<(RCOLS * 256 + 255) / 256, 256, 0, stream>>>(bases, comp, loopw, WT);
  convert_x_kernel<<<((MP * 256 / 4) + 255) / 256, 256, 0, stream>>>(node_feats, Xb);
  gemm_kernel<<<dim3(MP / 128, RCOLS / 128), 256, 0, stream>>>(Xb, WT, T);

  hipMemsetAsync(cnts, 0, NN * 4, stream);
  hipMemsetAsync(cur, 0, NN * 4, stream);
  count_kernel<<<(EE + 255) / 256, 256, 0, stream>>>(dst, cnts);
  scan_kernel<<<1, 1024, 0, stream>>>(cnts, offs);
  scatter_kernel<<<(EE + 255) / 256, 256, 0, stream>>>(src, dst, etype, offs, cur, eoff);

  finalize_kernel<<<NN / 4, 256, 0, stream>>>(T, offs, eoff, bias, gamma, beta, out);
}